// Round 1
// baseline (161.141 us; speedup 1.0000x reference)
//
#include <hip/hip_runtime.h>
#include <hip/hip_bf16.h>
#include <stdint.h>

typedef __attribute__((ext_vector_type(8))) short bf16x8;
typedef __attribute__((ext_vector_type(4))) float f32x4;
typedef __attribute__((ext_vector_type(4))) unsigned int u32x4;
typedef __attribute__((ext_vector_type(2))) unsigned int u32x2;
typedef unsigned short u16;
typedef unsigned int u32;

#define N_NODES 8192
#define N_EDGES 1024
#define F_DIM   256

__device__ __forceinline__ u16 f2bf(float f) {
    union { float f; u32 u; } v; v.f = f;
    u32 u = v.u;
    u = (u + 0x7FFFu + ((u >> 16) & 1u)) >> 16;   // round-nearest-even
    return (u16)u;
}

// ---------------------------------------------------------------------------
// prep_h: one pass over H [8192 x 1024] fp32.
//   - H_bf16  [8192 x 1024] (row-major, A-operand of GEMM2)
//   - Ht_bf16 [1024 x 8192] (transposed via LDS, Bt-operand of GEMM1)
//   - dv[8192] row sums, de[1024] col sums (exact: sums of 0/1 in fp32)
// 64x64 tile per block, 256 threads. grid (16, 128).
// ---------------------------------------------------------------------------
__global__ void prep_h(const float* __restrict__ H, u16* __restrict__ Hb,
                       u16* __restrict__ Ht, float* __restrict__ dv,
                       float* __restrict__ de) {
    __shared__ u16 tT[64 * 66];       // [c_local][r_local], stride 66 (pad)
    __shared__ float dv_s[64];
    __shared__ float de_s[64];
    const int tid = threadIdx.x;
    if (tid < 64) { dv_s[tid] = 0.f; de_s[tid] = 0.f; }
    __syncthreads();
    const int r0 = blockIdx.y * 64;   // node tile
    const int c0 = blockIdx.x * 64;   // edge tile
    const int lr = tid >> 4;          // 0..15
    const int lc = (tid & 15) * 4;    // 0..60
    float cs0 = 0.f, cs1 = 0.f, cs2 = 0.f, cs3 = 0.f;
#pragma unroll
    for (int i = 0; i < 4; i++) {
        const int row = r0 + lr + i * 16;
        f32x4 v = *(const f32x4*)(&H[(size_t)row * N_EDGES + c0 + lc]);
        atomicAdd(&dv_s[lr + i * 16], v[0] + v[1] + v[2] + v[3]);
        cs0 += v[0]; cs1 += v[1]; cs2 += v[2]; cs3 += v[3];
        const u16 b0 = f2bf(v[0]), b1 = f2bf(v[1]), b2 = f2bf(v[2]), b3 = f2bf(v[3]);
        u32x2 pk; pk[0] = (u32)b0 | ((u32)b1 << 16); pk[1] = (u32)b2 | ((u32)b3 << 16);
        *(u32x2*)(&Hb[(size_t)row * N_EDGES + c0 + lc]) = pk;
        tT[(lc + 0) * 66 + lr + i * 16] = b0;
        tT[(lc + 1) * 66 + lr + i * 16] = b1;
        tT[(lc + 2) * 66 + lr + i * 16] = b2;
        tT[(lc + 3) * 66 + lr + i * 16] = b3;
    }
    atomicAdd(&de_s[lc + 0], cs0);
    atomicAdd(&de_s[lc + 1], cs1);
    atomicAdd(&de_s[lc + 2], cs2);
    atomicAdd(&de_s[lc + 3], cs3);
    __syncthreads();
    if (tid < 64) {
        atomicAdd(&dv[r0 + tid], dv_s[tid]);
        atomicAdd(&de[c0 + tid], de_s[tid]);
    }
    // write transposed tile: Ht[e = c0+er][n = r0+lc .. +3]
#pragma unroll
    for (int i = 0; i < 4; i++) {
        const int er = lr + i * 16;
        const u16 b0 = tT[er * 66 + lc + 0];
        const u16 b1 = tT[er * 66 + lc + 1];
        const u16 b2 = tT[er * 66 + lc + 2];
        const u16 b3 = tT[er * 66 + lc + 3];
        u32x2 pk; pk[0] = (u32)b0 | ((u32)b1 << 16); pk[1] = (u32)b2 | ((u32)b3 << 16);
        *(u32x2*)(&Ht[(size_t)(c0 + er) * N_NODES + r0 + lc]) = pk;
    }
}

// ---------------------------------------------------------------------------
// prep_x: Xst[f][n] = bf16(X[n][f] * rsqrt(dv[n]))  -> [256 x 8192]
// 64x64 tile, grid (4, 128).
// ---------------------------------------------------------------------------
__global__ void prep_x(const float* __restrict__ X, const float* __restrict__ dv,
                       u16* __restrict__ Xst) {
    __shared__ u16 tT[64 * 66];
    const int tid = threadIdx.x;
    const int r0 = blockIdx.y * 64;   // node tile
    const int c0 = blockIdx.x * 64;   // feature tile
    const int lr = tid >> 4;
    const int lc = (tid & 15) * 4;
#pragma unroll
    for (int i = 0; i < 4; i++) {
        const int row = r0 + lr + i * 16;
        const float s = rsqrtf(dv[row]);
        f32x4 v = *(const f32x4*)(&X[(size_t)row * F_DIM + c0 + lc]);
        tT[(lc + 0) * 66 + lr + i * 16] = f2bf(v[0] * s);
        tT[(lc + 1) * 66 + lr + i * 16] = f2bf(v[1] * s);
        tT[(lc + 2) * 66 + lr + i * 16] = f2bf(v[2] * s);
        tT[(lc + 3) * 66 + lr + i * 16] = f2bf(v[3] * s);
    }
    __syncthreads();
#pragma unroll
    for (int i = 0; i < 4; i++) {
        const int er = lr + i * 16;
        const u16 b0 = tT[er * 66 + lc + 0];
        const u16 b1 = tT[er * 66 + lc + 1];
        const u16 b2 = tT[er * 66 + lc + 2];
        const u16 b3 = tT[er * 66 + lc + 3];
        u32x2 pk; pk[0] = (u32)b0 | ((u32)b1 << 16); pk[1] = (u32)b2 | ((u32)b3 << 16);
        *(u32x2*)(&Xst[(size_t)(c0 + er) * N_NODES + r0 + lc]) = pk;
    }
}

// W [256 x 256] fp32 -> bf16 (already the Bt layout for GEMM3)
__global__ void prep_w(const float* __restrict__ W, u16* __restrict__ Wb) {
    const int idx = (blockIdx.x * 256 + threadIdx.x) * 4;
    f32x4 v = *(const f32x4*)(W + idx);
    u32x2 pk;
    pk[0] = (u32)f2bf(v[0]) | ((u32)f2bf(v[1]) << 16);
    pk[1] = (u32)f2bf(v[2]) | ((u32)f2bf(v[3]) << 16);
    *(u32x2*)(&Wb[idx]) = pk;
}

// Mt[f][e] = bf16(Macc[f][e] / de[e])
__global__ void finalize_m(const float* __restrict__ Macc, const float* __restrict__ de,
                           u16* __restrict__ Mt) {
    const int idx = (blockIdx.x * 256 + threadIdx.x) * 4;
    const int e = idx & (N_EDGES - 1);
    f32x4 m = *(const f32x4*)(Macc + idx);
    f32x4 d = *(const f32x4*)(de + e);
    u32x2 pk;
    pk[0] = (u32)f2bf(m[0] / d[0]) | ((u32)f2bf(m[1] / d[1]) << 16);
    pk[1] = (u32)f2bf(m[2] / d[2]) | ((u32)f2bf(m[3] / d[3]) << 16);
    *(u32x2*)(&Mt[idx]) = pk;
}

// ---------------------------------------------------------------------------
// gemm_bt: C[M x N] = A[M x K] * Bt[N x K]^T, bf16 in, fp32 accumulate.
// 64x64 tile / block, 256 threads (4 waves in 2x2), BK=32, 16x16x32 MFMA.
// Fragment layouts (HW-verified, learn_hip m89/m91):
//   A: A[m = lane&15][k = quad*8 + j]   B: B[k = quad*8 + j][n = lane&15]
//   D: col = lane&15, row = quad*4 + reg
// EPI: 0 = atomicAdd fp32 (split-K partial, GEMM1)
//      1 = bf16 out, scale by rsqrt(rowScale[row])  (GEMM2)
//      2 = fp32 out, + bias[col]                    (GEMM3)
// ---------------------------------------------------------------------------
template <int EPI>
__global__ void gemm_bt(const u16* __restrict__ A, const u16* __restrict__ Bt,
                        int K, int lda, int ldb, int kSplit,
                        float* __restrict__ outF, u16* __restrict__ outB, int ldc,
                        const float* __restrict__ rowScale,
                        const float* __restrict__ bias) {
    __shared__ u16 As[64 * 40];   // row stride 40 (=80B, 16B-aligned, pad vs banks)
    __shared__ u16 Bs[64 * 40];
    const int tid = threadIdx.x;
    const int lane = tid & 63;
    const int wave = tid >> 6;
    const int wm = wave >> 1, wn = wave & 1;
    const int row16 = lane & 15;
    const int quad = lane >> 4;

    const int row0 = blockIdx.y * 64;
    const int col0 = blockIdx.x * 64;
    const int k0 = blockIdx.z * kSplit;
    const int k1 = k0 + kSplit;

    const int sr = tid >> 2;          // staging row 0..63
    const int sk = (tid & 3) * 8;     // 0,8,16,24

    const u16* gA = A + (size_t)(row0 + sr) * lda + sk;
    const u16* gB = Bt + (size_t)(col0 + sr) * ldb + sk;

    f32x4 acc[2][2] = {};

    for (int k = k0; k < k1; k += 32) {
        u32x4 va = *(const u32x4*)(gA + k);
        u32x4 vb = *(const u32x4*)(gB + k);
        *(u32x4*)(&As[sr * 40 + sk]) = va;
        *(u32x4*)(&Bs[sr * 40 + sk]) = vb;
        __syncthreads();
        bf16x8 af[2], bfr[2];
#pragma unroll
        for (int t = 0; t < 2; t++) {
            af[t]  = *(const bf16x8*)(&As[(wm * 32 + t * 16 + row16) * 40 + quad * 8]);
            bfr[t] = *(const bf16x8*)(&Bs[(wn * 32 + t * 16 + row16) * 40 + quad * 8]);
        }
#pragma unroll
        for (int tm = 0; tm < 2; tm++)
#pragma unroll
            for (int tn = 0; tn < 2; tn++)
                acc[tm][tn] = __builtin_amdgcn_mfma_f32_16x16x32_bf16(
                    af[tm], bfr[tn], acc[tm][tn], 0, 0, 0);
        __syncthreads();
    }

#pragma unroll
    for (int tm = 0; tm < 2; tm++) {
#pragma unroll
        for (int tn = 0; tn < 2; tn++) {
            const int col = col0 + wn * 32 + tn * 16 + row16;
#pragma unroll
            for (int r = 0; r < 4; r++) {
                const int row = row0 + wm * 32 + tm * 16 + quad * 4 + r;
                float v = acc[tm][tn][r];
                if (EPI == 0) {
                    atomicAdd(&outF[(size_t)row * ldc + col], v);
                } else if (EPI == 1) {
                    v *= rsqrtf(rowScale[row]);
                    outB[(size_t)row * ldc + col] = f2bf(v);
                } else {
                    outF[(size_t)row * ldc + col] = v + bias[col];
                }
            }
        }
    }
}

// ---------------------------------------------------------------------------
extern "C" void kernel_launch(void* const* d_in, const int* in_sizes, int n_in,
                              void* d_out, int out_size, void* d_ws, size_t ws_size,
                              hipStream_t stream) {
    (void)in_sizes; (void)n_in; (void)out_size; (void)ws_size;
    const float* X = (const float*)d_in[0];   // [8192 x 256]
    const float* H = (const float*)d_in[1];   // [8192 x 1024]
    const float* W = (const float*)d_in[2];   // [256 x 256]
    const float* b = (const float*)d_in[3];   // [256]
    float* out = (float*)d_out;               // [8192 x 256] fp32

    char* ws = (char*)d_ws;
    float* Macc = (float*)(ws);                       // 1 MB   [256 x 1024] fp32
    float* dv   = (float*)(ws + 0x100000);            // 32 KB
    float* de   = (float*)(ws + 0x108000);            // 4 KB
    u16*   Hb   = (u16*)(ws + 0x110000);              // 16 MB  [8192 x 1024]
    u16*   Ht   = (u16*)(ws + 0x1110000);             // 16 MB  [1024 x 8192]
    u16*   Xst  = (u16*)(ws + 0x2110000);             // 4 MB   [256 x 8192]
    u16*   Mt   = (u16*)(ws + 0x2510000);             // 512 KB [256 x 1024]
    u16*   Xn   = (u16*)(ws + 0x2590000);             // 4 MB   [8192 x 256]
    u16*   Wb   = (u16*)(ws + 0x2990000);             // 128 KB [256 x 256]

    // zero Macc + dv + de (contiguous prefix)
    hipMemsetAsync(ws, 0, 0x109000, stream);

    prep_h<<<dim3(16, 128), 256, 0, stream>>>(H, Hb, Ht, dv, de);
    prep_x<<<dim3(4, 128), 256, 0, stream>>>(X, dv, Xst);
    prep_w<<<64, 256, 0, stream>>>(W, Wb);

    // GEMM1: Mt_acc[f][e] = sum_n Xst[f][n] * Ht[e][n]; M=256, N=1024, K=8192
    // split-K = 8 -> 512 blocks
    gemm_bt<0><<<dim3(16, 4, 8), 256, 0, stream>>>(
        Xst, Ht, 8192, 8192, 8192, 1024, Macc, nullptr, 1024, nullptr, nullptr);

    finalize_m<<<256, 256, 0, stream>>>(Macc, de, Mt);

    // GEMM2: Xn[n][f] = rsqrt(dv[n]) * sum_e Hb[n][e] * Mt[f][e]; M=8192,N=256,K=1024
    gemm_bt<1><<<dim3(4, 128, 1), 256, 0, stream>>>(
        Hb, Mt, 1024, 1024, 1024, 1024, nullptr, Xn, 256, dv, nullptr);

    // GEMM3: out[n][j] = sum_f Xn[n][f] * Wb[j][f] + b[j]; M=8192,N=256,K=256
    gemm_bt<2><<<dim3(4, 128, 1), 256, 0, stream>>>(
        Xn, Wb, 256, 256, 256, 256, out, nullptr, 256, nullptr, b);
}